// Round 1
// baseline (345.019 us; speedup 1.0000x reference)
//
#include <hip/hip_runtime.h>
#include <hip/hip_bf16.h>
#include <stdint.h>

#define IN_F   4096
#define OUT_F  4096
#define BATCH  4096

typedef __bf16 bf16x8_t __attribute__((ext_vector_type(8)));
typedef float  f32x4_t  __attribute__((ext_vector_type(4)));
typedef float  f32x4v   __attribute__((ext_vector_type(4)));
typedef unsigned short u16x8_t __attribute__((ext_vector_type(8)));

#define AS_GLOBAL(p) ((const __attribute__((address_space(1))) void*)(p))
#define AS_LDS(p)    ((__attribute__((address_space(3))) void*)(p))

__device__ __forceinline__ unsigned short f32_to_bf16_rne(float f) {
    union { float f; uint32_t u; } v; v.f = f;
    uint32_t u = v.u;
    u += 0x7FFFu + ((u >> 16) & 1u);
    return (unsigned short)(u >> 16);
}

// ---------------------------------------------------------------------------
// Convert pass, rebuilt. Old single kernel ran at ~1.8 TB/s (29% of peak);
// this splits into two stream-simple kernels with plain (cacheable) loads,
// 16 B/lane stores, and 2 unrolled rounds per thread for MLP.
//   convert_x : xb = bf16(x)        1R+1W, 100.7 MB  -> ~17 us @ 6 TB/s
//   convert_wm: wb = bf16(w*m)      2R+1W, 167.8 MB  -> ~28 us @ 6 TB/s
// Each thread handles 8 floats per round via two dwordx4 loads at base and
// base+16 (one addr calc, offset:16 fold) and ONE dwordx4 (u16x8) store.
// Grid 4096x256, 2 rounds: 4096*256*2*8 = 16.78M elements = exactly 4096^2.
// ---------------------------------------------------------------------------
__global__ __launch_bounds__(256)
void convert_x_kernel(const float* __restrict__ x,
                      unsigned short* __restrict__ xb) {
    const int64_t t0 = (int64_t)blockIdx.x * 256 + threadIdx.x;   // 0..2^20-1
#pragma unroll
    for (int k = 0; k < 2; ++k) {
        const int64_t i = t0 + (int64_t)k * (1 << 20);  // u16x8 index
        f32x4_t a = ((const f32x4_t*)x)[2 * i];
        f32x4_t b = ((const f32x4_t*)x)[2 * i + 1];
        u16x8_t o;
        o[0] = f32_to_bf16_rne(a[0]);
        o[1] = f32_to_bf16_rne(a[1]);
        o[2] = f32_to_bf16_rne(a[2]);
        o[3] = f32_to_bf16_rne(a[3]);
        o[4] = f32_to_bf16_rne(b[0]);
        o[5] = f32_to_bf16_rne(b[1]);
        o[6] = f32_to_bf16_rne(b[2]);
        o[7] = f32_to_bf16_rne(b[3]);
        ((u16x8_t*)xb)[i] = o;
    }
}

__global__ __launch_bounds__(256)
void convert_wm_kernel(const float* __restrict__ w,
                       const float* __restrict__ m,
                       unsigned short* __restrict__ wb) {
    const int64_t t0 = (int64_t)blockIdx.x * 256 + threadIdx.x;
#pragma unroll
    for (int k = 0; k < 2; ++k) {
        const int64_t i = t0 + (int64_t)k * (1 << 20);
        f32x4_t wa = ((const f32x4_t*)w)[2 * i];
        f32x4_t wbv = ((const f32x4_t*)w)[2 * i + 1];
        f32x4_t ma = ((const f32x4_t*)m)[2 * i];
        f32x4_t mb = ((const f32x4_t*)m)[2 * i + 1];
        u16x8_t o;
        o[0] = f32_to_bf16_rne(wa[0] * ma[0]);
        o[1] = f32_to_bf16_rne(wa[1] * ma[1]);
        o[2] = f32_to_bf16_rne(wa[2] * ma[2]);
        o[3] = f32_to_bf16_rne(wa[3] * ma[3]);
        o[4] = f32_to_bf16_rne(wbv[0] * mb[0]);
        o[5] = f32_to_bf16_rne(wbv[1] * mb[1]);
        o[6] = f32_to_bf16_rne(wbv[2] * mb[2]);
        o[7] = f32_to_bf16_rne(wbv[3] * mb[3]);
        ((u16x8_t*)wb)[i] = o;
    }
}

// ---------------------------------------------------------------------------
// bf16 MFMA GEMM: y[b][o] = sum_k xb[b][k]*wb[o][k] + bias[o]
// UNCHANGED this round (at the 128^2/2-barrier structural ceiling, 928 TF).
// ---------------------------------------------------------------------------
#define BM 128
#define BN 128
#define BK 64

__global__ __launch_bounds__(256)
void gemm_bt_bias_kernel(const unsigned short* __restrict__ A,   // [BATCH][IN_F]
                         const unsigned short* __restrict__ B,   // [OUT_F][IN_F]
                         const float* __restrict__ bias,         // [OUT_F]
                         float* __restrict__ C) {                // [BATCH][OUT_F]
    __shared__ __align__(16) unsigned short sA[2][BM * BK];  // 2 x 16 KiB
    __shared__ __align__(16) unsigned short sB[2][BN * BK];  // 2 x 16 KiB

    const int t    = threadIdx.x;
    const int wv   = t >> 6;
    const int lane = t & 63;
    const int quad = lane >> 4;    // 0..3
    const int l16  = lane & 15;

    const int bm = blockIdx.y * BM;
    const int bn = blockIdx.x * BN;

    const int wr = wv >> 1;
    const int wc = wv & 1;

    // Staging: per round r of 4, thread t loads 16 B for
    //   row = r*32 + t/8, elem-col = 8*((t&7)^((t>>3)&7))  [swizzled by row&7]
    // landing at LDS linear byte offset r*4096 + t*16.
    const int srow = t >> 3;
    const int scol = 8 * ((t & 7) ^ ((t >> 3) & 7));
    const unsigned short* gA = A + (int64_t)(bm + srow) * IN_F + scol;
    const unsigned short* gB = B + (int64_t)(bn + srow) * IN_F + scol;

#define ISSUE_TILE(buf, k0)                                                   \
    do {                                                                      \
        _Pragma("unroll")                                                     \
        for (int r = 0; r < 4; ++r) {                                         \
            __builtin_amdgcn_global_load_lds(                                 \
                AS_GLOBAL(gA + (int64_t)r * 32 * IN_F + (k0)),                \
                AS_LDS((char*)sA[buf] + r * 4096 + wv * 1024 + lane * 16), 16, 0, 0); \
            __builtin_amdgcn_global_load_lds(                                 \
                AS_GLOBAL(gB + (int64_t)r * 32 * IN_F + (k0)),                \
                AS_LDS((char*)sB[buf] + r * 4096 + wv * 1024 + lane * 16), 16, 0, 0); \
        }                                                                     \
    } while (0)

    f32x4_t acc[4][4];
#pragma unroll
    for (int mi = 0; mi < 4; ++mi)
#pragma unroll
        for (int ni = 0; ni < 4; ++ni)
            acc[mi][ni] = (f32x4_t){0.f, 0.f, 0.f, 0.f};

    ISSUE_TILE(0, 0);

    int buf = 0;
    for (int k0 = 0; k0 < IN_F; k0 += BK, buf ^= 1) {
        // One barrier per iter: (a) drains glds into sA/sB[buf] (issued last
        // iter; vmcnt(0) before s_barrier), (b) all waves done reading
        // sA/sB[buf^1] -> safe to overwrite with the prefetch below.
        __syncthreads();

        if (k0 + BK < IN_F)
            ISSUE_TILE(buf ^ 1, k0 + BK);   // flies across the whole compute below

        const unsigned short* __restrict__ cA = sA[buf];
        const unsigned short* __restrict__ cB = sB[buf];

#pragma unroll
        for (int ks = 0; ks < 2; ++ks) {
            bf16x8_t af[4], bf[4];
#pragma unroll
            for (int mi = 0; mi < 4; ++mi) {
                const int row = wr * 64 + mi * 16 + l16;
                const int ch  = (ks * 4 + quad) ^ (row & 7);
                af[mi] = *(const bf16x8_t*)(cA + row * BK + ch * 8);
            }
#pragma unroll
            for (int ni = 0; ni < 4; ++ni) {
                const int row = wc * 64 + ni * 16 + l16;
                const int ch  = (ks * 4 + quad) ^ (row & 7);
                bf[ni] = *(const bf16x8_t*)(cB + row * BK + ch * 8);
            }
#pragma unroll
            for (int mi = 0; mi < 4; ++mi)
#pragma unroll
                for (int ni = 0; ni < 4; ++ni)
                    acc[mi][ni] = __builtin_amdgcn_mfma_f32_16x16x32_bf16(
                        af[mi], bf[ni], acc[mi][ni], 0, 0, 0);
        }
    }

    // Epilogue: C/D layout col = lane&15 (n), row = quad*4 + reg (m).
    float bv[4];
#pragma unroll
    for (int ni = 0; ni < 4; ++ni)
        bv[ni] = bias[bn + wc * 64 + ni * 16 + l16];

#pragma unroll
    for (int mi = 0; mi < 4; ++mi) {
        const int row0 = bm + wr * 64 + mi * 16 + quad * 4;
#pragma unroll
        for (int ni = 0; ni < 4; ++ni) {
            const int col = bn + wc * 64 + ni * 16 + l16;
#pragma unroll
            for (int reg = 0; reg < 4; ++reg)
                C[(int64_t)(row0 + reg) * OUT_F + col] = acc[mi][ni][reg] + bv[ni];
        }
    }
#undef ISSUE_TILE
}

// ---------------------------------------------------------------------------
// Fallback (workspace too small): plain fp32 tiled GEMM.
// ---------------------------------------------------------------------------
__global__ void fallback_gemm_kernel(const float* __restrict__ x,
                                     const float* __restrict__ w,
                                     const float* __restrict__ bias,
                                     const float* __restrict__ m,
                                     float* __restrict__ y) {
    __shared__ float sx[16][17];
    __shared__ float sw[16][17];
    const int tx = threadIdx.x, ty = threadIdx.y;
    const int row = blockIdx.y * 16 + ty;
    const int col = blockIdx.x * 16 + tx;
    float acc = 0.f;
    for (int k0 = 0; k0 < IN_F; k0 += 16) {
        sx[ty][tx] = x[(int64_t)row * IN_F + k0 + tx];
        const int64_t widx = (int64_t)(blockIdx.x * 16 + ty) * IN_F + k0 + tx;
        sw[ty][tx] = w[widx] * m[widx];
        __syncthreads();
#pragma unroll
        for (int kk = 0; kk < 16; ++kk)
            acc += sx[ty][kk] * sw[tx][kk];
        __syncthreads();
    }
    y[(int64_t)row * OUT_F + col] = acc + bias[col];
}

// ---------------------------------------------------------------------------
extern "C" void kernel_launch(void* const* d_in, const int* in_sizes, int n_in,
                              void* d_out, int out_size, void* d_ws, size_t ws_size,
                              hipStream_t stream) {
    const float* x    = (const float*)d_in[0];
    const float* w    = (const float*)d_in[1];
    const float* bias = (const float*)d_in[2];
    const float* m    = (const float*)d_in[3];
    float* y = (float*)d_out;

    const size_t need = (size_t)2 * (size_t)OUT_F * (size_t)IN_F * sizeof(unsigned short);

    if (ws_size >= need) {
        unsigned short* xb = (unsigned short*)d_ws;
        unsigned short* wb = xb + (size_t)BATCH * IN_F;

        convert_x_kernel<<<4096, 256, 0, stream>>>(x, xb);
        convert_wm_kernel<<<4096, 256, 0, stream>>>(w, m, wb);

        dim3 grid(OUT_F / BN, BATCH / BM);   // 32 x 32 = 1024 blocks
        gemm_bt_bias_kernel<<<grid, 256, 0, stream>>>(xb, wb, bias, y);
    } else {
        dim3 grid(OUT_F / 16, BATCH / 16);
        dim3 block(16, 16);
        fallback_gemm_kernel<<<grid, block, 0, stream>>>(x, w, bias, m, y);
    }
}